// Round 4
// baseline (575.250 us; speedup 1.0000x reference)
//
#include <hip/hip_runtime.h>
#include <hip/hip_bf16.h>
#include <type_traits>

// ---------------------------------------------------------------------------
// PerceiverAttention on MI355X.
// Pipeline:
//   1) transpose_all     : Wkv/Wq/Wo -> bf16 [N][K] layouts
//   2) ln_kernel         : LayerNorm src+ltn -> ctx bf16 [66048][768] (+qin)
//   3) gemm256_bt        : kv = ctx @ WkvT^T -> bf16 [66048][1024]
//                          256^2 tile, 8-wave, 4-phase/K-tile, K-HALF staging
//                          units, counted vmcnt(8) 2x/tile, 4 barriers/tile
//   4) gemm_bt<float>    : q   = qin @ WqT^T    -> f32  [512][512]
//   5) attn_flash        : split-K MFMA flash attention, wave-local softmax
//      attn_combine      : merge 16 splits -> out_pre bf16 [512][512]
//   6) gemm_bt<float>    : out = out_pre @ WoT^T -> f32 d_out [512][768]
// ---------------------------------------------------------------------------

#define N_SRC 8192
#define N_LTN 64
#define N_CTX 8256            // per (b,t)
#define NBT 8                 // b*t
#define MROWS 66048           // NBT * N_CTX
#define DIMK 768
#define DEMB 512
#define NSPLIT 16
#define NTILES 65             // ceil(N_CTX / 128)

typedef short short8 __attribute__((ext_vector_type(8)));
typedef float floatx4 __attribute__((ext_vector_type(4)));
typedef __attribute__((address_space(1))) void gvoid;
typedef __attribute__((address_space(3))) void lvoid;

__device__ inline ushort f2bf(float f) {
    union { float f; unsigned u; } v; v.f = f;
    unsigned u = v.u;
    return (ushort)((u + 0x7fffu + ((u >> 16) & 1u)) >> 16);   // RNE
}

// --------------------------- weight transposes -----------------------------
__global__ __launch_bounds__(256) void transpose_all(
        const float* __restrict__ Wkv, const float* __restrict__ Wq,
        const float* __restrict__ Wo, ushort* __restrict__ WkvT,
        ushort* __restrict__ WqT, ushort* __restrict__ WoT) {
    __shared__ ushort tile[64][65];
    int z = blockIdx.z;
    const float* in; ushort* out; int R, C;
    if (z == 0)      { in = Wkv; out = WkvT; R = 768; C = 1024; }
    else if (z == 1) { in = Wq;  out = WqT;  R = 768; C = 512;  }
    else             { in = Wo;  out = WoT;  R = 512; C = 768;  }
    int C0 = blockIdx.x * 64, R0 = blockIdx.y * 64;
    if (C0 >= C || R0 >= R) return;
    int tc = threadIdx.x & 63, tr4 = threadIdx.x >> 6;
#pragma unroll
    for (int j = 0; j < 16; j++) {
        int r = tr4 + j * 4;
        tile[r][tc] = f2bf(in[(size_t)(R0 + r) * C + C0 + tc]);
    }
    __syncthreads();
#pragma unroll
    for (int j = 0; j < 16; j++) {
        int c = tr4 + j * 4;
        out[(size_t)(C0 + c) * R + R0 + tc] = tile[tc][c];
    }
}

// ------------------------------ layernorm ----------------------------------
__global__ __launch_bounds__(256) void ln_kernel(
        const float* __restrict__ src, const float* __restrict__ ltn,
        const float* __restrict__ gs, const float* __restrict__ bs,
        const float* __restrict__ gl, const float* __restrict__ bl,
        ushort* __restrict__ ctx, ushort* __restrict__ qin) {
    int r = blockIdx.x * 4 + (threadIdx.x >> 6);
    int lane = threadIdx.x & 63;
    int bt = r / N_CTX;
    int i = r - bt * N_CTX;
    const float *x, *g, *b;
    int isl = (i >= N_SRC);
    if (!isl) { x = src + ((size_t)bt * N_SRC + i) * DIMK; g = gs; b = bs; }
    else      { x = ltn + ((size_t)bt * N_LTN + (i - N_SRC)) * DIMK; g = gl; b = bl; }
    float4 v[3]; float s = 0.f, s2 = 0.f;
#pragma unroll
    for (int t = 0; t < 3; t++) {
        float4 xv = *(const float4*)(x + t * 256 + lane * 4);
        v[t] = xv;
        s  += xv.x + xv.y + xv.z + xv.w;
        s2 += xv.x * xv.x + xv.y * xv.y + xv.z * xv.z + xv.w * xv.w;
    }
#pragma unroll
    for (int off = 32; off >= 1; off >>= 1) {
        s  += __shfl_xor(s,  off, 64);
        s2 += __shfl_xor(s2, off, 64);
    }
    float mu  = s * (1.0f / 768.0f);
    float var = s2 * (1.0f / 768.0f) - mu * mu;
    float rs  = rsqrtf(var + 1e-5f);
    ushort* crow = ctx + (size_t)r * DIMK;
    ushort* qrow = isl ? (qin + (size_t)(bt * N_LTN + (i - N_SRC)) * DIMK) : nullptr;
#pragma unroll
    for (int t = 0; t < 3; t++) {
        int idx = t * 256 + lane * 4;
        float4 gv = *(const float4*)(g + idx);
        float4 bv = *(const float4*)(b + idx);
        ushort4 u;
        u.x = f2bf((v[t].x - mu) * rs * gv.x + bv.x);
        u.y = f2bf((v[t].y - mu) * rs * gv.y + bv.y);
        u.z = f2bf((v[t].z - mu) * rs * gv.z + bv.z);
        u.w = f2bf((v[t].w - mu) * rs * gv.w + bv.w);
        *(ushort4*)(crow + idx) = u;
        if (isl) *(ushort4*)(qrow + idx) = u;
    }
}

// ------------------------------- GEMM (128^2) ------------------------------
// C[M][N] = A[M][K] @ B[N][K]^T , A/B bf16, acc fp32. T1 XCD swizzle applied
// (proven R3: FETCH 400->75 MB on the kv shape).
template <typename CT>
__global__ __launch_bounds__(256) void gemm_bt(
        const ushort* __restrict__ A, const ushort* __restrict__ B,
        CT* __restrict__ C, int M, int N, int K) {
    __shared__ ushort lA[128 * 64];
    __shared__ ushort lB[128 * 64];
    int tid = threadIdx.x;
    int lane = tid & 63, wave = tid >> 6;
    int wm = wave >> 1, wn = wave & 1;

    int nwg = gridDim.x * gridDim.y;
    int lin = blockIdx.y * gridDim.x + blockIdx.x;
    int swz = (lin & 7) * (nwg >> 3) + (lin >> 3);
    int bn = swz % gridDim.x, bm = swz / gridDim.x;

    floatx4 acc[4][4];
#pragma unroll
    for (int mi = 0; mi < 4; mi++)
#pragma unroll
        for (int ni = 0; ni < 4; ni++) acc[mi][ni] = (floatx4){0.f, 0.f, 0.f, 0.f};

    int srow = lane >> 3;
    int schunk = (lane & 7) ^ srow;
    int quad = lane >> 4, lr = lane & 15;
    const int kiters = K >> 6;

    for (int kt = 0; kt < kiters; kt++) {
#pragma unroll
        for (int c2 = 0; c2 < 4; c2++) {
            int row = c2 * 32 + wave * 8 + srow;
            const ushort* gpA = A + ((size_t)(bm * 128 + row) * K + kt * 64 + schunk * 8);
            ushort* lpA = lA + (c2 * 32 + wave * 8) * 64 + lane * 8;
            __builtin_amdgcn_global_load_lds((gvoid*)gpA, (lvoid*)lpA, 16, 0, 0);
            const ushort* gpB = B + ((size_t)(bn * 128 + row) * K + kt * 64 + schunk * 8);
            ushort* lpB = lB + (c2 * 32 + wave * 8) * 64 + lane * 8;
            __builtin_amdgcn_global_load_lds((gvoid*)gpB, (lvoid*)lpB, 16, 0, 0);
        }
        __syncthreads();
#pragma unroll
        for (int ks = 0; ks < 2; ks++) {
            short8 av[4], bv[4];
            int slot = ((ks * 4 + quad) ^ (lane & 7)) * 8;
#pragma unroll
            for (int mi = 0; mi < 4; mi++)
                av[mi] = *(const short8*)(lA + (wm * 64 + mi * 16 + lr) * 64 + slot);
#pragma unroll
            for (int ni = 0; ni < 4; ni++)
                bv[ni] = *(const short8*)(lB + (wn * 64 + ni * 16 + lr) * 64 + slot);
#pragma unroll
            for (int mi = 0; mi < 4; mi++)
#pragma unroll
                for (int ni = 0; ni < 4; ni++)
                    acc[mi][ni] = __builtin_amdgcn_mfma_f32_16x16x32_bf16(
                        av[mi], bv[ni], acc[mi][ni], 0, 0, 0);
        }
        __syncthreads();
    }
#pragma unroll
    for (int mi = 0; mi < 4; mi++)
#pragma unroll
        for (int ni = 0; ni < 4; ni++)
#pragma unroll
            for (int r = 0; r < 4; r++) {
                int row = bm * 128 + wm * 64 + mi * 16 + quad * 4 + r;
                int col = bn * 128 + wn * 64 + ni * 16 + lr;
                float vv = acc[mi][ni][r];
                if constexpr (std::is_same<CT, ushort>::value)
                    C[(size_t)row * N + col] = f2bf(vv);
                else
                    C[(size_t)row * N + col] = vv;
            }
}

// -------- 256x256 pipelined GEMM: K-HALF stage units, 4-phase/K-tile -------
// Round-4 schedule (self-consistent ledger; fixes R1's 1-phase publish
// distance and R2's monolithic convoy):
//   Stage unit = 256 rows x 32 k (one kk-half of A or B, 16 KB, 2 loads/thr).
//   LDS [buf][kk][256][32]: kk0 slot is dead after phase 2 of the tile that
//   reads it, so tile t+2's kk0 stages DURING tile t -> every unit has a
//   5-6 phase (~3000 cyc) issue->publish distance, >> 900-cyc HBM latency.
//   Per K-tile t (cur = t&1, nxt = cur^1):
//     p1: stage (t+1).A-kk1 -> lA[nxt][1] | read A0x4,B0x4 | MFMA 16 | BAR
//     p2: stage (t+1).B-kk1 -> lB[nxt][1] | read A0(mh1)x4 | MFMA 16
//         | vmcnt(8) (publishes (t).kk1, issued 5-6 phases ago) | BAR
//     p3: stage (t+2).A-kk0 -> lA[cur][0] (slot freed at p2-end barrier)
//         | read A1x4,B1x4 | MFMA 16 | BAR
//     p4: stage (t+2).B-kk0 -> lB[cur][0] | read A1(mh1)x4 | MFMA 16
//         | vmcnt(8) (publishes (t+1).kk0) | BAR
//   vmcnt(8) = 4 newest units (8 loads) may stay in flight; never drains to 0
//   in-loop. 4 barriers/tile (one per phase); each wave's lgkm drain before
//   its MFMA makes the end-of-phase barrier a safe WAR fence for the slot
//   staged next phase. Tail stages issue unconditionally with clamped k-index
//   (keeps vmcnt ledger wave-uniform; writes land in dead slots).
//   Swizzle: stored chunk p = c ^ ((row>>1)&3), applied as inverse on the
//   global source (linear LDS dest, rule #21) and on the ds_read address.
//   T1 XCD swizzle + T5 setprio kept.
template <typename CT>
__global__ __launch_bounds__(512, 2) void gemm256_bt(
        const ushort* __restrict__ A, const ushort* __restrict__ B,
        CT* __restrict__ C, int M, int N, int K) {
    __shared__ ushort lA[2][2][256 * 32];   // [buf][kk][row][chunk*8]
    __shared__ ushort lB[2][2][256 * 32];

    int tid = threadIdx.x;
    int lane = tid & 63, w = tid >> 6;
    int wm = w >> 2, wn = w & 3;          // 2 (M) x 4 (N) wave grid
    int quad = lane >> 4, lr = lane & 15;

    int ntile = N >> 8;
    int nwg = gridDim.x;
    int lin = blockIdx.x;
    int swz = (lin & 7) * (nwg >> 3) + (lin >> 3);   // 8 XCDs, nwg%8==0
    int bn = swz % ntile, bm = swz / ntile;

    const int kiters = K >> 6;

    // ---- staging: one K-half unit (256 rows x 32 k), 2 loads/thread ----
    // load i covers rows (w*2+i)*16 .. +15; lane L: row += L>>2, stored
    // chunk p = L&3, global chunk c = p ^ ((row>>1)&3). Dest is linear:
    // unit + (w*2+i)*16*32 + L*8.
    const ushort* aRow = A + (size_t)(bm * 256) * K;
    const ushort* bRow = B + (size_t)(bn * 256) * K;

    auto stageU = [&](ushort* unit, const ushort* gbase, int ktv, int kk) {
#pragma unroll
        for (int i = 0; i < 2; i++) {
            int row = (w * 2 + i) * 16 + (lane >> 2);
            int p = lane & 3;
            int c = p ^ ((row >> 1) & 3);
            const ushort* g = gbase + (size_t)row * K + ktv * 64 + kk * 32 + c * 8;
            ushort* d = unit + (w * 2 + i) * 16 * 32 + lane * 8;
            __builtin_amdgcn_global_load_lds((gvoid*)g, (lvoid*)d, 16, 0, 0);
        }
    };

    floatx4 acc[8][4];
#pragma unroll
    for (int m = 0; m < 8; m++)
#pragma unroll
        for (int n = 0; n < 4; n++) acc[m][n] = (floatx4){0.f, 0.f, 0.f, 0.f};

#define G256_FENCE asm volatile("" ::: "memory")
#define G256_BAR do { G256_FENCE; __builtin_amdgcn_s_barrier(); G256_FENCE; } while (0)
#define G256_VM8 asm volatile("s_waitcnt vmcnt(8)" ::: "memory")

    // frag read helpers (swizzled chunk)
    auto rdA = [&](const ushort* unit, int m) -> short8 {
        int row = wm * 128 + m * 16 + lr;
        int p = quad ^ ((row >> 1) & 3);
        return *(const short8*)(unit + row * 32 + p * 8);
    };
    auto rdB = [&](const ushort* unit, int n) -> short8 {
        int row = wn * 64 + n * 16 + lr;
        int p = quad ^ ((row >> 1) & 3);
        return *(const short8*)(unit + row * 32 + p * 8);
    };

    // ---- prologue: units in ledger order: t0.A0 B0 A1 B1, t1.A0 B0 ----
    stageU(lA[0][0], aRow, 0, 0);
    stageU(lB[0][0], bRow, 0, 0);
    stageU(lA[0][1], aRow, 0, 1);
    stageU(lB[0][1], bRow, 0, 1);
    if (kiters > 1) {
        stageU(lA[1][0], aRow, 1, 0);
        stageU(lB[1][0], bRow, 1, 0);
    } else {                     // degenerate; keep counts uniform
        stageU(lA[1][0], aRow, 0, 0);
        stageU(lB[1][0], bRow, 0, 0);
    }
    G256_VM8;    // waits t0.A0,B0 (4 newer units allowed outstanding)
    G256_BAR;

    for (int kt = 0; kt < kiters; kt++) {
        int cur = kt & 1, nxt = cur ^ 1;
        int k1 = (kt + 1 < kiters) ? kt + 1 : kiters - 1;   // clamp (dead slot)
        int k2 = (kt + 2 < kiters) ? kt + 2 : kiters - 1;

        short8 af[4], bf[4];

        // ---------- phase 1: kk0, mh0 ----------
        stageU(lA[nxt][1], aRow, k1, 1);          // (t+1).A-kk1
#pragma unroll
        for (int fi = 0; fi < 4; fi++) af[fi] = rdA(lA[cur][0], fi);
#pragma unroll
        for (int fj = 0; fj < 4; fj++) bf[fj] = rdB(lB[cur][0], fj);
        __builtin_amdgcn_s_setprio(1);
#pragma unroll
        for (int fi = 0; fi < 4; fi++)
#pragma unroll
            for (int fj = 0; fj < 4; fj++)
                acc[fi][fj] = __builtin_amdgcn_mfma_f32_16x16x32_bf16(
                    af[fi], bf[fj], acc[fi][fj], 0, 0, 0);
        __builtin_amdgcn_s_setprio(0);
        G256_BAR;

        // ---------- phase 2: kk0, mh1 (B held in regs) ----------
        stageU(lB[nxt][1], bRow, k1, 1);          // (t+1).B-kk1
#pragma unroll
        for (int fi = 0; fi < 4; fi++) af[fi] = rdA(lA[cur][0], 4 + fi);
        __builtin_amdgcn_s_setprio(1);
#pragma unroll
        for (int fi = 0; fi < 4; fi++)
#pragma unroll
            for (int fj = 0; fj < 4; fj++)
                acc[4 + fi][fj] = __builtin_amdgcn_mfma_f32_16x16x32_bf16(
                    af[fi], bf[fj], acc[4 + fi][fj], 0, 0, 0);
        __builtin_amdgcn_s_setprio(0);
        G256_VM8;                                  // publish (t).kk1
        G256_BAR;

        // ---------- phase 3: kk1, mh0 ----------
        stageU(lA[cur][0], aRow, k2, 0);          // (t+2).A-kk0 (slot freed)
#pragma unroll
        for (int fi = 0; fi < 4; fi++) af[fi] = rdA(lA[cur][1], fi);
#pragma unroll
        for (int fj = 0; fj < 4; fj++) bf[fj] = rdB(lB[cur][1], fj);
        __builtin_amdgcn_s_setprio(1);
#pragma unroll
        for (int fi = 0; fi < 4; fi++)
#pragma unroll
            for (int fj = 0; fj < 4; fj++)
                acc[fi][fj] = __builtin_amdgcn_mfma_f32_16x16x32_bf16(
                    af[fi], bf[fj], acc[fi][fj], 0, 0, 0);
        __builtin_amdgcn_s_setprio(0);
        G256_BAR;

        // ---------- phase 4: kk1, mh1 ----------
        stageU(lB[cur][0], bRow, k2, 0);          // (t+2).B-kk0
#pragma unroll
        for (int fi = 0; fi < 4; fi++) af[fi] = rdA(lA[cur][1], 4 + fi);
        __builtin_amdgcn_s_setprio(1);
#pragma unroll
        for (int fi = 0; fi < 4; fi++)
#pragma unroll
            for (int fj = 0; fj < 4; fj++)
                acc[4 + fi][fj] = __builtin_amdgcn_mfma_f32_16x16x32_bf16(
                    af[fi], bf[fj], acc[4 + fi][fj], 0, 0, 0);
        __builtin_amdgcn_s_setprio(0);
        G256_VM8;                                  // publish (t+1).kk0
        G256_BAR;
    }
    asm volatile("s_waitcnt vmcnt(0)" ::: "memory");  // drain before epilogue

#undef G256_FENCE
#undef G256_BAR
#undef G256_VM8

    const int crb = bm * 256 + wm * 128 + quad * 4;
    const int ccb = bn * 256 + wn * 64 + lr;
#pragma unroll
    for (int m = 0; m < 8; m++)
#pragma unroll
        for (int n = 0; n < 4; n++)
#pragma unroll
            for (int r = 0; r < 4; r++) {
                int row = crb + m * 16 + r;
                float vv = acc[m][n][r];
                if constexpr (std::is_same<CT, ushort>::value)
                    C[(size_t)row * N + ccb + n * 16] = f2bf(vv);
                else
                    C[(size_t)row * N + ccb + n * 16] = vv;
            }
}

// ------------------------- flash attention (split-K) -----------------------
#define PR 136

__global__ __launch_bounds__(256) void attn_flash(
        const float* __restrict__ qf, const ushort* __restrict__ kvb,
        float* __restrict__ Op, float* __restrict__ ml) {
    __shared__ ushort lK[128 * 64];
    __shared__ ushort lVT[64 * PR];   // [d 0..63][key 0..127]
    __shared__ ushort lP[64 * PR];    // [qrow 0..63][key 0..127], wave-private rows

    int comb = blockIdx.x, split = blockIdx.y;
    int bt = comb >> 3, h = comb & 7;
    int tid = threadIdx.x;
    int w = tid >> 6, lane = tid & 63, quad = lane >> 4, lr = lane & 15;

    const ushort* kptr = kvb + (size_t)bt * N_CTX * 1024 + h * 64;
    const ushort* vptr = kptr + 512;

    short8 qa[2];
    {
        const float* p0 = qf + (size_t)(bt * 64 + w * 16 + lr) * DEMB + h * 64;
#pragma unroll
        for (int kc = 0; kc < 2; kc++) {
            const float* p = p0 + kc * 32 + quad * 8;
            float4 f0 = *(const float4*)p;
            float4 f1 = *(const float4*)(p + 4);
            short8 v;
            v[0] = f2bf(f0.x); v[1] = f2bf(f0.y); v[2] = f2bf(f0.z); v[3] = f2bf(f0.w);
            v[4] = f2bf(f1.x); v[5] = f2bf(f1.y); v[6] = f2bf(f1.z); v[7] = f2bf(f1.w);
            qa[kc] = v;
        }
    }

    floatx4 accO[4];
#pragma unroll
    for (int nt = 0; nt < 4; nt++) accO[nt] = (floatx4){0.f, 0.f, 0.f, 0.f};
    float m_run[4], l_run[4];
#pragma unroll
    for (int r = 0; r < 4; r++) { m_run[r] = -1e30f; l_run[r] = 0.f; }

    for (int t = split; t < NTILES; t += NSPLIT) {
        int kbase = t * 128;
        __syncthreads();   // prev-iter lK/lVT readers done before restaging

#pragma unroll
        for (int c2 = 0; c2 < 4; c2++) {
            int jloc = w * 32 + c2 * 8 + (lane >> 3);
            int chunk = (lane & 7) ^ ((lane >> 3) & 7);
            int jg = kbase + jloc; if (jg > N_CTX - 1) jg = N_CTX - 1;  // clamp tail
            const ushort* gp = kptr + (size_t)jg * 1024 + chunk * 8;
            ushort* lp = lK + (w * 32 + c2 * 8) * 64 + lane * 8;
            __builtin_amdgcn_global_load_lds((gvoid*)gp, (lvoid*)lp, 16, 0, 0);
        }

        {
            int k0 = kbase + lane * 2;
            bool valid = (k0 + 1) < N_CTX;
            int k0c = valid ? k0 : (N_CTX - 2);
            const ushort* r0 = vptr + (size_t)k0c * 1024 + w * 16;
            const ushort* r1 = r0 + 1024;
            uint4 a0 = *(const uint4*)r0;
            uint4 a1 = *(const uint4*)(r0 + 8);
            uint4 b0 = *(const uint4*)r1;
            uint4 b1 = *(const uint4*)(r1 + 8);
            if (!valid) {
                a0 = make_uint4(0, 0, 0, 0); a1 = a0; b0 = a0; b1 = a0;
            }
            unsigned av8[8] = {a0.x, a0.y, a0.z, a0.w, a1.x, a1.y, a1.z, a1.w};
            unsigned bv8[8] = {b0.x, b0.y, b0.z, b0.w, b1.x, b1.y, b1.z, b1.w};
#pragma unroll
            for (int i = 0; i < 8; i++) {
                unsigned la = av8[i] & 0xffffu, ha = av8[i] >> 16;
                unsigned lb = bv8[i] & 0xffffu, hb = bv8[i] >> 16;
                *(unsigned*)(lVT + (w * 16 + 2 * i) * PR + lane * 2)     = la | (lb << 16);
                *(unsigned*)(lVT + (w * 16 + 2 * i + 1) * PR + lane * 2) = ha | (hb << 16);
            }
        }
        __syncthreads();   // staging complete

        floatx4 accS[8];
#pragma unroll
        for (int nt = 0; nt < 8; nt++) accS[nt] = (floatx4){0.f, 0.f, 0.f, 0.f};
#pragma unroll
        for (int kc = 0; kc < 2; kc++) {
#pragma unroll
            for (int nt = 0; nt < 8; nt++) {
                int kr = nt * 16 + lr;
                int slot = (kc * 4 + quad) ^ (kr & 7);
                short8 bv = *(const short8*)(lK + kr * 64 + slot * 8);
                accS[nt] = __builtin_amdgcn_mfma_f32_16x16x32_bf16(
                    qa[kc], bv, accS[nt], 0, 0, 0);
            }
        }

        float sc[8][4];
        float tmax[4] = {-1e30f, -1e30f, -1e30f, -1e30f};
#pragma unroll
        for (int nt = 0; nt < 8; nt++) {
            bool vk = (kbase + nt * 16 + lr) < N_CTX;
#pragma unroll
            for (int r = 0; r < 4; r++) {
                float s = vk ? accS[nt][r] * 0.125f : -1e30f;
                sc[nt][r] = s;
                tmax[r] = fmaxf(tmax[r], s);
            }
        }
#pragma unroll
        for (int r = 0; r < 4; r++) {
#pragma unroll
            for (int d = 1; d < 16; d <<= 1) tmax[r] = fmaxf(tmax[r], __shfl_xor(tmax[r], d, 64));
        }
        float alpha[4], lsum[4];
#pragma unroll
        for (int r = 0; r < 4; r++) {
            float mn = fmaxf(m_run[r], tmax[r]);
            alpha[r] = __expf(m_run[r] - mn);
            m_run[r] = mn;
            lsum[r] = 0.f;
        }

#pragma unroll
        for (int nt = 0; nt < 8; nt++) {
#pragma unroll
            for (int r = 0; r < 4; r++) {
                float p = __expf(sc[nt][r] - m_run[r]);
                lsum[r] += p;
                lP[(w * 16 + quad * 4 + r) * PR + nt * 16 + lr] = f2bf(p);
            }
        }
#pragma unroll
        for (int r = 0; r < 4; r++) {
#pragma unroll
            for (int d = 1; d < 16; d <<= 1) lsum[r] += __shfl_xor(lsum[r], d, 64);
            l_run[r] = l_run[r] * alpha[r] + lsum[r];
        }
#pragma unroll
        for (int nt = 0; nt < 4; nt++) {
            accO[nt][0] *= alpha[0]; accO[nt][1] *= alpha[1];
            accO[nt][2] *= alpha[2]; accO[nt][3] *= alpha[3];
        }

        short8 av[4];
#pragma unroll
        for (int kc = 0; kc < 4; kc++)
            av[kc] = *(const short8*)(lP + (w * 16 + lr) * PR + kc * 32 + quad * 8);
#pragma unroll
        for (int nt = 0; nt < 4; nt++)
#pragma unroll
            for (int kc = 0; kc < 4; kc++) {
                short8 bv = *(const short8*)(lVT + (nt * 16 + lr) * PR + kc * 32 + quad * 8);
                accO[nt] = __builtin_amdgcn_mfma_f32_16x16x32_bf16(av[kc], bv, accO[nt], 0, 0, 0);
            }
    }

    float* opb = Op + (size_t)(comb * NSPLIT + split) * 64 * 64;
#pragma unroll
    for (int nt = 0; nt < 4; nt++)
#pragma unroll
        for (int r = 0; r < 4; r++)
            opb[(w * 16 + quad * 4 + r) * 64 + nt * 16 + lr] = accO[nt][r];
    if (lr == 0) {
#pragma unroll
        for (int r = 0; r < 4; r++) {
            int row = w * 16 + quad * 4 + r;
            float* mlp = ml + ((size_t)(comb * NSPLIT + split) * 64 + row) * 2;
            mlp[0] = m_run[r]; mlp[1] = l_run[r];
        }
    }
}

__global__ __launch_bounds__(64) void attn_combine(
        const float* __restrict__ Op, const float* __restrict__ ml,
        ushort* __restrict__ outp) {
    int bx = blockIdx.x;
    int comb = bx >> 6, q = bx & 63;
    int bt = comb >> 3, h = comb & 7;
    int d = threadIdx.x;
    float M = -1e30f;
    for (int s = 0; s < NSPLIT; s++)
        M = fmaxf(M, ml[((size_t)(comb * NSPLIT + s) * 64 + q) * 2]);
    float L = 0.f, O = 0.f;
    for (int s = 0; s < NSPLIT; s++) {
        const float* p = ml + ((size_t)(comb * NSPLIT + s) * 64 + q) * 2;
        float wgt = __expf(p[0] - M);
        L = fmaf(wgt, p[1], L);
        O = fmaf(wgt, Op[((size_t)(comb * NSPLIT + s) * 64 + q) * 64 + d], O);
    }
    outp[(size_t)(bt * 64 + q) * DEMB + h * 64 + d] = f2bf(O / L);
}

// ------------------------------ launcher -----------------------------------
extern "C" void kernel_launch(void* const* d_in, const int* in_sizes, int n_in,
                              void* d_out, int out_size, void* d_ws, size_t ws_size,
                              hipStream_t stream) {
    const float* src   = (const float*)d_in[0];
    const float* ltn   = (const float*)d_in[1];
    const float* g_src = (const float*)d_in[2];
    const float* b_src = (const float*)d_in[3];
    const float* g_ltn = (const float*)d_in[4];
    const float* b_ltn = (const float*)d_in[5];
    const float* Wq    = (const float*)d_in[6];
    const float* Wkv   = (const float*)d_in[7];
    const float* Wo    = (const float*)d_in[8];
    float* out = (float*)d_out;

    char* ws = (char*)d_ws;
    size_t off = 0;
    auto alloc = [&](size_t bytes) -> void* {
        void* p = ws + off;
        off += (bytes + 255) & ~(size_t)255;
        return p;
    };
    ushort* ctx  = (ushort*)alloc((size_t)MROWS * DIMK * 2);   // 101.4 MB
    ushort* qin  = (ushort*)alloc((size_t)512 * DIMK * 2);
    ushort* WkvT = (ushort*)alloc((size_t)1024 * DIMK * 2);
    ushort* WqT  = (ushort*)alloc((size_t)512 * DIMK * 2);
    ushort* WoT  = (ushort*)alloc((size_t)768 * DEMB * 2);
    ushort* kvb  = (ushort*)alloc((size_t)MROWS * 1024 * 2);   // 135.3 MB
    float*  qf   = (float*) alloc((size_t)512 * DEMB * 4);
    ushort* outp = (ushort*)alloc((size_t)512 * DEMB * 2);

    float* Op  = (float*)(void*)ctx;                       // partials alias ctx
    float* mlb = Op + (size_t)64 * NSPLIT * 64 * 64;

    transpose_all<<<dim3(16, 12, 3), 256, 0, stream>>>(Wkv, Wq, Wo, WkvT, WqT, WoT);

    ln_kernel<<<MROWS / 4, 256, 0, stream>>>(src, ltn, g_src, b_src, g_ltn, b_ltn, ctx, qin);

    // KV projection: 256^2 pipelined GEMM. grid = 258*4 = 1032 (1032 % 8 == 0)
    gemm256_bt<ushort><<<dim3((MROWS / 256) * (1024 / 256)), 512, 0, stream>>>(
        ctx, WkvT, kvb, MROWS, 1024, DIMK);
    gemm_bt<float><<<dim3(512 / 128, 512 / 128), 256, 0, stream>>>(
        qin, WqT, qf, 512, 512, DIMK);

    attn_flash<<<dim3(64, NSPLIT), 256, 0, stream>>>(qf, kvb, Op, mlb);
    attn_combine<<<4096, 64, 0, stream>>>(Op, mlb, outp);

    gemm_bt<float><<<dim3(768 / 128, 512 / 128), 256, 0, stream>>>(
        outp, WoT, out, 512, 768, DEMB);
}

// Round 5
// 559.653 us; speedup vs baseline: 1.0279x; 1.0279x over previous
//
#include <hip/hip_runtime.h>
#include <hip/hip_bf16.h>
#include <type_traits>

// ---------------------------------------------------------------------------
// PerceiverAttention on MI355X.
// Pipeline (5 launches):
//   1) prep_kernel   : [fused] Wkv/Wq/Wo transposes -> bf16 [N][K]  AND
//                      LayerNorm src+ltn -> ctx bf16 [66048][768] (+qin)
//   2) gemm_kvq      : [fused] kv = ctx @ WkvT^T -> bf16 [66048][1024] (4128 blk)
//                      AND q = qin @ WqT^T -> f32 [512][512] (16 blk, fills tail)
//                      128^2 tile m97 structure + T1 XCD swizzle (proven R3)
//   3) attn_flash    : split-K MFMA flash attention, wave-local softmax
//   4) attn_combine  : merge 16 splits -> out_pre bf16 [512][512]
//   5) gemm_bt<float>: out = out_pre @ WoT^T -> f32 d_out [512][768]
// History: three 256^2 deep-pipeline ports (R1 185us / R2 169us / R4 206us)
// all lost to this 128^2 kernel (157us) on this shape -- K=768 has only 12
// K-tiles, too short to amortize the 8-phase pipeline. KV GEMM is frozen.
// ---------------------------------------------------------------------------

#define N_SRC 8192
#define N_LTN 64
#define N_CTX 8256            // per (b,t)
#define NBT 8                 // b*t
#define MROWS 66048           // NBT * N_CTX
#define DIMK 768
#define DEMB 512
#define NSPLIT 16
#define NTILES 65             // ceil(N_CTX / 128)

#define LN_BLOCKS (MROWS / 4)     // 16512
#define TR_BLOCKS 576             // 16 x 12 x 3
#define KV_BLOCKS 4128            // 8 x 516
#define Q_BLOCKS  16              // 4 x 4

typedef short short8 __attribute__((ext_vector_type(8)));
typedef float floatx4 __attribute__((ext_vector_type(4)));
typedef __attribute__((address_space(1))) void gvoid;
typedef __attribute__((address_space(3))) void lvoid;

__device__ inline ushort f2bf(float f) {
    union { float f; unsigned u; } v; v.f = f;
    unsigned u = v.u;
    return (ushort)((u + 0x7fffu + ((u >> 16) & 1u)) >> 16);   // RNE
}

// ------------------- prep: weight transposes + layernorm -------------------
// blocks [0, LN_BLOCKS)            : LayerNorm (4 rows/block, 1 wave/row)
// blocks [LN_BLOCKS, +TR_BLOCKS)   : 64x64 LDS-tiled transpose of Wkv/Wq/Wo
// The two halves are independent; fusing removes one launch + fills the
// transpose's 576-block launch slot with useful LN work.
__global__ __launch_bounds__(256) void prep_kernel(
        const float* __restrict__ src, const float* __restrict__ ltn,
        const float* __restrict__ gs, const float* __restrict__ bs,
        const float* __restrict__ gl, const float* __restrict__ bl,
        ushort* __restrict__ ctx, ushort* __restrict__ qin,
        const float* __restrict__ Wkv, const float* __restrict__ Wq,
        const float* __restrict__ Wo, ushort* __restrict__ WkvT,
        ushort* __restrict__ WqT, ushort* __restrict__ WoT) {
    __shared__ ushort tile[64][65];
    int bid = blockIdx.x;

    if (bid < LN_BLOCKS) {
        // ---------------- layernorm ----------------
        int r = bid * 4 + (threadIdx.x >> 6);
        int lane = threadIdx.x & 63;
        int bt = r / N_CTX;
        int i = r - bt * N_CTX;
        const float *x, *g, *b;
        int isl = (i >= N_SRC);
        if (!isl) { x = src + ((size_t)bt * N_SRC + i) * DIMK; g = gs; b = bs; }
        else      { x = ltn + ((size_t)bt * N_LTN + (i - N_SRC)) * DIMK; g = gl; b = bl; }
        float4 v[3]; float s = 0.f, s2 = 0.f;
#pragma unroll
        for (int t = 0; t < 3; t++) {
            float4 xv = *(const float4*)(x + t * 256 + lane * 4);
            v[t] = xv;
            s  += xv.x + xv.y + xv.z + xv.w;
            s2 += xv.x * xv.x + xv.y * xv.y + xv.z * xv.z + xv.w * xv.w;
        }
#pragma unroll
        for (int off = 32; off >= 1; off >>= 1) {
            s  += __shfl_xor(s,  off, 64);
            s2 += __shfl_xor(s2, off, 64);
        }
        float mu  = s * (1.0f / 768.0f);
        float var = s2 * (1.0f / 768.0f) - mu * mu;
        float rs  = rsqrtf(var + 1e-5f);
        ushort* crow = ctx + (size_t)r * DIMK;
        ushort* qrow = isl ? (qin + (size_t)(bt * N_LTN + (i - N_SRC)) * DIMK) : nullptr;
#pragma unroll
        for (int t = 0; t < 3; t++) {
            int idx = t * 256 + lane * 4;
            float4 gv = *(const float4*)(g + idx);
            float4 bv = *(const float4*)(b + idx);
            ushort4 u;
            u.x = f2bf((v[t].x - mu) * rs * gv.x + bv.x);
            u.y = f2bf((v[t].y - mu) * rs * gv.y + bv.y);
            u.z = f2bf((v[t].z - mu) * rs * gv.z + bv.z);
            u.w = f2bf((v[t].w - mu) * rs * gv.w + bv.w);
            *(ushort4*)(crow + idx) = u;
            if (isl) *(ushort4*)(qrow + idx) = u;
        }
        return;
    }

    // ---------------- weight transpose ----------------
    int bid2 = bid - LN_BLOCKS;          // [0, 576): x 16, y 12, z 3
    int z = bid2 / 192;
    int rem = bid2 - z * 192;
    int by = rem >> 4, bx = rem & 15;
    const float* in; ushort* out; int R, C;
    if (z == 0)      { in = Wkv; out = WkvT; R = 768; C = 1024; }
    else if (z == 1) { in = Wq;  out = WqT;  R = 768; C = 512;  }
    else             { in = Wo;  out = WoT;  R = 512; C = 768;  }
    int C0 = bx * 64, R0 = by * 64;
    if (C0 >= C || R0 >= R) return;      // uniform early-out (before any sync)
    int tc = threadIdx.x & 63, tr4 = threadIdx.x >> 6;
#pragma unroll
    for (int j = 0; j < 16; j++) {
        int r = tr4 + j * 4;
        tile[r][tc] = f2bf(in[(size_t)(R0 + r) * C + C0 + tc]);
    }
    __syncthreads();
#pragma unroll
    for (int j = 0; j < 16; j++) {
        int c = tr4 + j * 4;
        out[(size_t)(C0 + c) * R + R0 + tc] = tile[tc][c];
    }
}

// --------------- fused KV + Q projection GEMM (128^2, K=768) ---------------
// blocks [0, KV_BLOCKS)        : kvb[66048][1024] = ctx @ WkvT^T (bf16 out)
//                                with T1 XCD-chunked swizzle (proven R3:
//                                FETCH 400 -> 75 MB)
// blocks [KV_BLOCKS, +Q_BLOCKS): qf[512][512] = qin @ WqT^T (f32 out); these
//                                16 blocks run in the KV dispatch's ragged
//                                tail round instead of a dedicated launch.
// Body identical to the verified gemm_bt (m97 structure, XOR chunk swizzle).
__global__ __launch_bounds__(256) void gemm_kvq(
        const ushort* __restrict__ ctx, const ushort* __restrict__ WkvT,
        ushort* __restrict__ kvb, const ushort* __restrict__ qin,
        const ushort* __restrict__ WqT, float* __restrict__ qf) {
    __shared__ ushort lA[128 * 64];
    __shared__ ushort lB[128 * 64];
    int tid = threadIdx.x;
    int lane = tid & 63, wave = tid >> 6;
    int wm = wave >> 1, wn = wave & 1;

    int lin = blockIdx.x;
    const ushort *A, *B;
    int bm, bn, N;
    bool bfout;
    if (lin < KV_BLOCKS) {
        int swz = (lin & 7) * (KV_BLOCKS >> 3) + (lin >> 3);   // T1, 4128%8==0
        bn = swz & 7; bm = swz >> 3;                           // gridx was 8
        A = ctx; B = WkvT; N = 1024; bfout = true;
    } else {
        int l2 = lin - KV_BLOCKS;
        bn = l2 & 3; bm = l2 >> 2;                             // 4 x 4
        A = qin; B = WqT; N = 512; bfout = false;
    }
    const int K = DIMK;                                        // 768 for both

    floatx4 acc[4][4];
#pragma unroll
    for (int mi = 0; mi < 4; mi++)
#pragma unroll
        for (int ni = 0; ni < 4; ni++) acc[mi][ni] = (floatx4){0.f, 0.f, 0.f, 0.f};

    int srow = lane >> 3;
    int schunk = (lane & 7) ^ srow;
    int quad = lane >> 4, lr = lane & 15;
    const int kiters = K >> 6;                                 // 12

    for (int kt = 0; kt < kiters; kt++) {
#pragma unroll
        for (int c2 = 0; c2 < 4; c2++) {
            int row = c2 * 32 + wave * 8 + srow;
            const ushort* gpA = A + ((size_t)(bm * 128 + row) * K + kt * 64 + schunk * 8);
            ushort* lpA = lA + (c2 * 32 + wave * 8) * 64 + lane * 8;
            __builtin_amdgcn_global_load_lds((gvoid*)gpA, (lvoid*)lpA, 16, 0, 0);
            const ushort* gpB = B + ((size_t)(bn * 128 + row) * K + kt * 64 + schunk * 8);
            ushort* lpB = lB + (c2 * 32 + wave * 8) * 64 + lane * 8;
            __builtin_amdgcn_global_load_lds((gvoid*)gpB, (lvoid*)lpB, 16, 0, 0);
        }
        __syncthreads();
#pragma unroll
        for (int ks = 0; ks < 2; ks++) {
            short8 av[4], bv[4];
            int slot = ((ks * 4 + quad) ^ (lane & 7)) * 8;
#pragma unroll
            for (int mi = 0; mi < 4; mi++)
                av[mi] = *(const short8*)(lA + (wm * 64 + mi * 16 + lr) * 64 + slot);
#pragma unroll
            for (int ni = 0; ni < 4; ni++)
                bv[ni] = *(const short8*)(lB + (wn * 64 + ni * 16 + lr) * 64 + slot);
#pragma unroll
            for (int mi = 0; mi < 4; mi++)
#pragma unroll
                for (int ni = 0; ni < 4; ni++)
                    acc[mi][ni] = __builtin_amdgcn_mfma_f32_16x16x32_bf16(
                        av[mi], bv[ni], acc[mi][ni], 0, 0, 0);
        }
        __syncthreads();
    }
#pragma unroll
    for (int mi = 0; mi < 4; mi++)
#pragma unroll
        for (int ni = 0; ni < 4; ni++)
#pragma unroll
            for (int r = 0; r < 4; r++) {
                int row = bm * 128 + wm * 64 + mi * 16 + quad * 4 + r;
                int col = bn * 128 + wn * 64 + ni * 16 + lr;
                float vv = acc[mi][ni][r];
                if (bfout) kvb[(size_t)row * 1024 + col] = f2bf(vv);
                else       qf[(size_t)row * 512 + col] = vv;
            }
}

// ------------------------------- GEMM (128^2) ------------------------------
// C[M][N] = A[M][K] @ B[N][K]^T , A/B bf16, acc fp32. T1 XCD swizzle
// (nwg must be %8==0; final out-gemm grid is 24). Used for the Wo GEMM.
template <typename CT>
__global__ __launch_bounds__(256) void gemm_bt(
        const ushort* __restrict__ A, const ushort* __restrict__ B,
        CT* __restrict__ C, int M, int N, int K) {
    __shared__ ushort lA[128 * 64];
    __shared__ ushort lB[128 * 64];
    int tid = threadIdx.x;
    int lane = tid & 63, wave = tid >> 6;
    int wm = wave >> 1, wn = wave & 1;

    int nwg = gridDim.x * gridDim.y;
    int lin = blockIdx.y * gridDim.x + blockIdx.x;
    int swz = (lin & 7) * (nwg >> 3) + (lin >> 3);
    int bn = swz % gridDim.x, bm = swz / gridDim.x;

    floatx4 acc[4][4];
#pragma unroll
    for (int mi = 0; mi < 4; mi++)
#pragma unroll
        for (int ni = 0; ni < 4; ni++) acc[mi][ni] = (floatx4){0.f, 0.f, 0.f, 0.f};

    int srow = lane >> 3;
    int schunk = (lane & 7) ^ srow;
    int quad = lane >> 4, lr = lane & 15;
    const int kiters = K >> 6;

    for (int kt = 0; kt < kiters; kt++) {
#pragma unroll
        for (int c2 = 0; c2 < 4; c2++) {
            int row = c2 * 32 + wave * 8 + srow;
            const ushort* gpA = A + ((size_t)(bm * 128 + row) * K + kt * 64 + schunk * 8);
            ushort* lpA = lA + (c2 * 32 + wave * 8) * 64 + lane * 8;
            __builtin_amdgcn_global_load_lds((gvoid*)gpA, (lvoid*)lpA, 16, 0, 0);
            const ushort* gpB = B + ((size_t)(bn * 128 + row) * K + kt * 64 + schunk * 8);
            ushort* lpB = lB + (c2 * 32 + wave * 8) * 64 + lane * 8;
            __builtin_amdgcn_global_load_lds((gvoid*)gpB, (lvoid*)lpB, 16, 0, 0);
        }
        __syncthreads();
#pragma unroll
        for (int ks = 0; ks < 2; ks++) {
            short8 av[4], bv[4];
            int slot = ((ks * 4 + quad) ^ (lane & 7)) * 8;
#pragma unroll
            for (int mi = 0; mi < 4; mi++)
                av[mi] = *(const short8*)(lA + (wm * 64 + mi * 16 + lr) * 64 + slot);
#pragma unroll
            for (int ni = 0; ni < 4; ni++)
                bv[ni] = *(const short8*)(lB + (wn * 64 + ni * 16 + lr) * 64 + slot);
#pragma unroll
            for (int mi = 0; mi < 4; mi++)
#pragma unroll
                for (int ni = 0; ni < 4; ni++)
                    acc[mi][ni] = __builtin_amdgcn_mfma_f32_16x16x32_bf16(
                        av[mi], bv[ni], acc[mi][ni], 0, 0, 0);
        }
        __syncthreads();
    }
#pragma unroll
    for (int mi = 0; mi < 4; mi++)
#pragma unroll
        for (int ni = 0; ni < 4; ni++)
#pragma unroll
            for (int r = 0; r < 4; r++) {
                int row = bm * 128 + wm * 64 + mi * 16 + quad * 4 + r;
                int col = bn * 128 + wn * 64 + ni * 16 + lr;
                float vv = acc[mi][ni][r];
                if constexpr (std::is_same<CT, ushort>::value)
                    C[(size_t)row * N + col] = f2bf(vv);
                else
                    C[(size_t)row * N + col] = vv;
            }
}

// ------------------------- flash attention (split-K) -----------------------
// Wave-local softmax: wave w owns Q/O rows [w*16, w*16+16). Per 128-key tile:
// S rows for ALL 128 keys live in-wave (8 C-frags); online-softmax reductions
// are 16-lane shfl_xor. lP is wave-private. 2 __syncthreads per tile.
// PR = 136 keeps lP/lVT rows 16B-aligned with 2-way bank aliasing (free).
#define PR 136

__global__ __launch_bounds__(256) void attn_flash(
        const float* __restrict__ qf, const ushort* __restrict__ kvb,
        float* __restrict__ Op, float* __restrict__ ml) {
    __shared__ ushort lK[128 * 64];
    __shared__ ushort lVT[64 * PR];   // [d 0..63][key 0..127]
    __shared__ ushort lP[64 * PR];    // [qrow 0..63][key 0..127], wave-private rows

    int comb = blockIdx.x, split = blockIdx.y;
    int bt = comb >> 3, h = comb & 7;
    int tid = threadIdx.x;
    int w = tid >> 6, lane = tid & 63, quad = lane >> 4, lr = lane & 15;

    const ushort* kptr = kvb + (size_t)bt * N_CTX * 1024 + h * 64;
    const ushort* vptr = kptr + 512;

    short8 qa[2];
    {
        const float* p0 = qf + (size_t)(bt * 64 + w * 16 + lr) * DEMB + h * 64;
#pragma unroll
        for (int kc = 0; kc < 2; kc++) {
            const float* p = p0 + kc * 32 + quad * 8;
            float4 f0 = *(const float4*)p;
            float4 f1 = *(const float4*)(p + 4);
            short8 v;
            v[0] = f2bf(f0.x); v[1] = f2bf(f0.y); v[2] = f2bf(f0.z); v[3] = f2bf(f0.w);
            v[4] = f2bf(f1.x); v[5] = f2bf(f1.y); v[6] = f2bf(f1.z); v[7] = f2bf(f1.w);
            qa[kc] = v;
        }
    }

    floatx4 accO[4];
#pragma unroll
    for (int nt = 0; nt < 4; nt++) accO[nt] = (floatx4){0.f, 0.f, 0.f, 0.f};
    float m_run[4], l_run[4];
#pragma unroll
    for (int r = 0; r < 4; r++) { m_run[r] = -1e30f; l_run[r] = 0.f; }

    for (int t = split; t < NTILES; t += NSPLIT) {
        int kbase = t * 128;
        __syncthreads();   // prev-iter lK/lVT readers done before restaging

#pragma unroll
        for (int c2 = 0; c2 < 4; c2++) {
            int jloc = w * 32 + c2 * 8 + (lane >> 3);
            int chunk = (lane & 7) ^ ((lane >> 3) & 7);
            int jg = kbase + jloc; if (jg > N_CTX - 1) jg = N_CTX - 1;  // clamp tail
            const ushort* gp = kptr + (size_t)jg * 1024 + chunk * 8;
            ushort* lp = lK + (w * 32 + c2 * 8) * 64 + lane * 8;
            __builtin_amdgcn_global_load_lds((gvoid*)gp, (lvoid*)lp, 16, 0, 0);
        }

        {
            int k0 = kbase + lane * 2;
            bool valid = (k0 + 1) < N_CTX;
            int k0c = valid ? k0 : (N_CTX - 2);
            const ushort* r0 = vptr + (size_t)k0c * 1024 + w * 16;
            const ushort* r1 = r0 + 1024;
            uint4 a0 = *(const uint4*)r0;
            uint4 a1 = *(const uint4*)(r0 + 8);
            uint4 b0 = *(const uint4*)r1;
            uint4 b1 = *(const uint4*)(r1 + 8);
            if (!valid) {
                a0 = make_uint4(0, 0, 0, 0); a1 = a0; b0 = a0; b1 = a0;
            }
            unsigned av8[8] = {a0.x, a0.y, a0.z, a0.w, a1.x, a1.y, a1.z, a1.w};
            unsigned bv8[8] = {b0.x, b0.y, b0.z, b0.w, b1.x, b1.y, b1.z, b1.w};
#pragma unroll
            for (int i = 0; i < 8; i++) {
                unsigned la = av8[i] & 0xffffu, ha = av8[i] >> 16;
                unsigned lb = bv8[i] & 0xffffu, hb = bv8[i] >> 16;
                *(unsigned*)(lVT + (w * 16 + 2 * i) * PR + lane * 2)     = la | (lb << 16);
                *(unsigned*)(lVT + (w * 16 + 2 * i + 1) * PR + lane * 2) = ha | (hb << 16);
            }
        }
        __syncthreads();   // staging complete

        floatx4 accS[8];
#pragma unroll
        for (int nt = 0; nt < 8; nt++) accS[nt] = (floatx4){0.f, 0.f, 0.f, 0.f};
#pragma unroll
        for (int kc = 0; kc < 2; kc++) {
#pragma unroll
            for (int nt = 0; nt < 8; nt++) {
                int kr = nt * 16 + lr;
                int slot = (kc * 4 + quad) ^ (kr & 7);
                short8 bv = *(const short8*)(lK + kr * 64 + slot * 8);
                accS[nt] = __builtin_amdgcn_mfma_f32_16x16x32_bf16(
                    qa[kc], bv, accS[nt], 0, 0, 0);
            }
        }

        float sc[8][4];
        float tmax[4] = {-1e30f, -1e30f, -1e30f, -1e30f};
#pragma unroll
        for (int nt = 0; nt < 8; nt++) {
            bool vk = (kbase + nt * 16 + lr) < N_CTX;
#pragma unroll
            for (int r = 0; r < 4; r++) {
                float s = vk ? accS[nt][r] * 0.125f : -1e30f;
                sc[nt][r] = s;
                tmax[r] = fmaxf(tmax[r], s);
            }
        }
#pragma unroll
        for (int r = 0; r < 4; r++) {
#pragma unroll
            for (int d = 1; d < 16; d <<= 1) tmax[r] = fmaxf(tmax[r], __shfl_xor(tmax[r], d, 64));
        }
        float alpha[4], lsum[4];
#pragma unroll
        for (int r = 0; r < 4; r++) {
            float mn = fmaxf(m_run[r], tmax[r]);
            alpha[r] = __expf(m_run[r] - mn);
            m_run[r] = mn;
            lsum[r] = 0.f;
        }

#pragma unroll
        for (int nt = 0; nt < 8; nt++) {
#pragma unroll
            for (int r = 0; r < 4; r++) {
                float p = __expf(sc[nt][r] - m_run[r]);
                lsum[r] += p;
                lP[(w * 16 + quad * 4 + r) * PR + nt * 16 + lr] = f2bf(p);
            }
        }
#pragma unroll
        for (int r = 0; r < 4; r++) {
#pragma unroll
            for (int d = 1; d < 16; d <<= 1) lsum[r] += __shfl_xor(lsum[r], d, 64);
            l_run[r] = l_run[r] * alpha[r] + lsum[r];
        }
#pragma unroll
        for (int nt = 0; nt < 4; nt++) {
            accO[nt][0] *= alpha[0]; accO[nt][1] *= alpha[1];
            accO[nt][2] *= alpha[2]; accO[nt][3] *= alpha[3];
        }

        short8 av[4];
#pragma unroll
        for (int kc = 0; kc < 4; kc++)
            av[kc] = *(const short8*)(lP + (w * 16 + lr) * PR + kc * 32 + quad * 8);
#pragma unroll
        for (int nt = 0; nt < 4; nt++)
#pragma unroll
            for (int kc = 0; kc < 4; kc++) {
                short8 bv = *(const short8*)(lVT + (nt * 16 + lr) * PR + kc * 32 + quad * 8);
                accO[nt] = __builtin_amdgcn_mfma_f32_16x16x32_bf16(av[kc], bv, accO[nt], 0, 0, 0);
            }
    }

    float* opb = Op + (size_t)(comb * NSPLIT + split) * 64 * 64;
#pragma unroll
    for (int nt = 0; nt < 4; nt++)
#pragma unroll
        for (int r = 0; r < 4; r++)
            opb[(w * 16 + quad * 4 + r) * 64 + nt * 16 + lr] = accO[nt][r];
    if (lr == 0) {
#pragma unroll
        for (int r = 0; r < 4; r++) {
            int row = w * 16 + quad * 4 + r;
            float* mlp = ml + ((size_t)(comb * NSPLIT + split) * 64 + row) * 2;
            mlp[0] = m_run[r]; mlp[1] = l_run[r];
        }
    }
}

__global__ __launch_bounds__(64) void attn_combine(
        const float* __restrict__ Op, const float* __restrict__ ml,
        ushort* __restrict__ outp) {
    int bx = blockIdx.x;
    int comb = bx >> 6, q = bx & 63;
    int bt = comb >> 3, h = comb & 7;
    int d = threadIdx.x;
    float M = -1e30f;
    for (int s = 0; s < NSPLIT; s++)
        M = fmaxf(M, ml[((size_t)(comb * NSPLIT + s) * 64 + q) * 2]);
    float L = 0.f, O = 0.f;
    for (int s = 0; s < NSPLIT; s++) {
        const float* p = ml + ((size_t)(comb * NSPLIT + s) * 64 + q) * 2;
        float wgt = __expf(p[0] - M);
        L = fmaf(wgt, p[1], L);
        O = fmaf(wgt, Op[((size_t)(comb * NSPLIT + s) * 64 + q) * 64 + d], O);
    }
    outp[(size_t)(bt * 64 + q) * DEMB + h * 64 + d] = f2bf(O / L);
}

// ------------------------------ launcher -----------------------------------
extern "C" void kernel_launch(void* const* d_in, const int* in_sizes, int n_in,
                              void* d_out, int out_size, void* d_ws, size_t ws_size,
                              hipStream_t stream) {
    const float* src   = (const float*)d_in[0];
    const float* ltn   = (const float*)d_in[1];
    const float* g_src = (const float*)d_in[2];
    const float* b_src = (const float*)d_in[3];
    const float* g_ltn = (const float*)d_in[4];
    const float* b_ltn = (const float*)d_in[5];
    const float* Wq    = (const float*)d_in[6];
    const float* Wkv   = (const float*)d_in[7];
    const float* Wo    = (const float*)d_in[8];
    float* out = (float*)d_out;

    char* ws = (char*)d_ws;
    size_t off = 0;
    auto alloc = [&](size_t bytes) -> void* {
        void* p = ws + off;
        off += (bytes + 255) & ~(size_t)255;
        return p;
    };
    ushort* ctx  = (ushort*)alloc((size_t)MROWS * DIMK * 2);   // 101.4 MB
    ushort* qin  = (ushort*)alloc((size_t)512 * DIMK * 2);
    ushort* WkvT = (ushort*)alloc((size_t)1024 * DIMK * 2);
    ushort* WqT  = (ushort*)alloc((size_t)512 * DIMK * 2);
    ushort* WoT  = (ushort*)alloc((size_t)768 * DEMB * 2);
    ushort* kvb  = (ushort*)alloc((size_t)MROWS * 1024 * 2);   // 135.3 MB
    float*  qf   = (float*) alloc((size_t)512 * DEMB * 4);
    ushort* outp = (ushort*)alloc((size_t)512 * DEMB * 2);

    // attention partials alias the ctx buffer (dead after the fused GEMM)
    float* Op  = (float*)(void*)ctx;                       // 16.8 MB
    float* mlb = Op + (size_t)64 * NSPLIT * 64 * 64;

    // 1) transposes + layernorm (independent halves, one launch)
    prep_kernel<<<LN_BLOCKS + TR_BLOCKS, 256, 0, stream>>>(
        src, ltn, g_src, b_src, g_ltn, b_ltn, ctx, qin,
        Wkv, Wq, Wo, WkvT, WqT, WoT);

    // 2) KV projection (4128 blk, T1 swizzle) + Q projection (16 blk in tail)
    gemm_kvq<<<KV_BLOCKS + Q_BLOCKS, 256, 0, stream>>>(
        ctx, WkvT, kvb, qin, WqT, qf);

    // 3-4) attention
    attn_flash<<<dim3(64, NSPLIT), 256, 0, stream>>>(qf, kvb, Op, mlb);
    attn_combine<<<4096, 64, 0, stream>>>(Op, mlb, outp);

    // 5) output projection (grid 24, 24%8==0 for T1)
    gemm_bt<float><<<dim3(768 / 128, 512 / 128), 256, 0, stream>>>(
        outp, WoT, out, 512, 768, DEMB);
}

// Round 6
// 508.830 us; speedup vs baseline: 1.1305x; 1.0999x over previous
//
#include <hip/hip_runtime.h>
#include <hip/hip_bf16.h>
#include <type_traits>

// ---------------------------------------------------------------------------
// PerceiverAttention on MI355X.
// Pipeline (5 launches):
//   1) prep_kernel   : [fused] Wkv/Wq/Wo transposes -> bf16 [N][K]  AND
//                      LayerNorm src+ltn -> ctx bf16 [66048][768] (+qin)
//   2) gemm_kvq      : [fused] kv = ctx @ WkvT^T -> bf16 [66048][1024] (4128 blk)
//                      AND q = qin @ WqT^T -> bf16 [512][512] (16 blk in tail)
//                      128^2 m97 structure + T1 XCD swizzle. UNIFIED bf16
//                      epilogue (R5's dual f32/bf16 path cost +16 VGPR ->
//                      occupancy 26->18% -> +52us; q output is consumed as
//                      bf16 by attn anyway, so bf16 store is bit-identical).
//   3) attn_flash    : split-K MFMA flash attention, wave-local softmax
//   4) attn_combine  : merge 16 splits -> out_pre bf16 [512][512]
//   5) gemm_bt<float>: out = out_pre @ WoT^T -> f32 d_out [512][768]
// History: three 256^2 deep-pipeline ports (R1 185 / R2 169 / R4 206us) all
// lost to the 128^2 kernel (157us) -- K=768 (12 K-tiles) can't amortize the
// deep pipeline. KV GEMM inner loop is frozen at the m97 structure.
// ---------------------------------------------------------------------------

#define N_SRC 8192
#define N_LTN 64
#define N_CTX 8256            // per (b,t)
#define NBT 8                 // b*t
#define MROWS 66048           // NBT * N_CTX
#define DIMK 768
#define DEMB 512
#define NSPLIT 16
#define NTILES 65             // ceil(N_CTX / 128)

#define LN_BLOCKS (MROWS / 4)     // 16512
#define TR_BLOCKS 576             // 16 x 12 x 3
#define KV_BLOCKS 4128            // 8 x 516
#define Q_BLOCKS  16              // 4 x 4

typedef short short8 __attribute__((ext_vector_type(8)));
typedef float floatx4 __attribute__((ext_vector_type(4)));
typedef __attribute__((address_space(1))) void gvoid;
typedef __attribute__((address_space(3))) void lvoid;

__device__ inline ushort f2bf(float f) {
    union { float f; unsigned u; } v; v.f = f;
    unsigned u = v.u;
    return (ushort)((u + 0x7fffu + ((u >> 16) & 1u)) >> 16);   // RNE
}

// ------------------- prep: weight transposes + layernorm -------------------
// blocks [0, LN_BLOCKS)            : LayerNorm (4 rows/block, 1 wave/row)
// blocks [LN_BLOCKS, +TR_BLOCKS)   : 64x64 LDS-tiled transpose of Wkv/Wq/Wo
__global__ __launch_bounds__(256) void prep_kernel(
        const float* __restrict__ src, const float* __restrict__ ltn,
        const float* __restrict__ gs, const float* __restrict__ bs,
        const float* __restrict__ gl, const float* __restrict__ bl,
        ushort* __restrict__ ctx, ushort* __restrict__ qin,
        const float* __restrict__ Wkv, const float* __restrict__ Wq,
        const float* __restrict__ Wo, ushort* __restrict__ WkvT,
        ushort* __restrict__ WqT, ushort* __restrict__ WoT) {
    __shared__ ushort tile[64][65];
    int bid = blockIdx.x;

    if (bid < LN_BLOCKS) {
        // ---------------- layernorm ----------------
        int r = bid * 4 + (threadIdx.x >> 6);
        int lane = threadIdx.x & 63;
        int bt = r / N_CTX;
        int i = r - bt * N_CTX;
        const float *x, *g, *b;
        int isl = (i >= N_SRC);
        if (!isl) { x = src + ((size_t)bt * N_SRC + i) * DIMK; g = gs; b = bs; }
        else      { x = ltn + ((size_t)bt * N_LTN + (i - N_SRC)) * DIMK; g = gl; b = bl; }
        float4 v[3]; float s = 0.f, s2 = 0.f;
#pragma unroll
        for (int t = 0; t < 3; t++) {
            float4 xv = *(const float4*)(x + t * 256 + lane * 4);
            v[t] = xv;
            s  += xv.x + xv.y + xv.z + xv.w;
            s2 += xv.x * xv.x + xv.y * xv.y + xv.z * xv.z + xv.w * xv.w;
        }
#pragma unroll
        for (int off = 32; off >= 1; off >>= 1) {
            s  += __shfl_xor(s,  off, 64);
            s2 += __shfl_xor(s2, off, 64);
        }
        float mu  = s * (1.0f / 768.0f);
        float var = s2 * (1.0f / 768.0f) - mu * mu;
        float rs  = rsqrtf(var + 1e-5f);
        ushort* crow = ctx + (size_t)r * DIMK;
        ushort* qrow = isl ? (qin + (size_t)(bt * N_LTN + (i - N_SRC)) * DIMK) : nullptr;
#pragma unroll
        for (int t = 0; t < 3; t++) {
            int idx = t * 256 + lane * 4;
            float4 gv = *(const float4*)(g + idx);
            float4 bv = *(const float4*)(b + idx);
            ushort4 u;
            u.x = f2bf((v[t].x - mu) * rs * gv.x + bv.x);
            u.y = f2bf((v[t].y - mu) * rs * gv.y + bv.y);
            u.z = f2bf((v[t].z - mu) * rs * gv.z + bv.z);
            u.w = f2bf((v[t].w - mu) * rs * gv.w + bv.w);
            *(ushort4*)(crow + idx) = u;
            if (isl) *(ushort4*)(qrow + idx) = u;
        }
        return;
    }

    // ---------------- weight transpose ----------------
    int bid2 = bid - LN_BLOCKS;          // [0, 576): x 16, y 12, z 3
    int z = bid2 / 192;
    int rem = bid2 - z * 192;
    int by = rem >> 4, bx = rem & 15;
    const float* in; ushort* out; int R, C;
    if (z == 0)      { in = Wkv; out = WkvT; R = 768; C = 1024; }
    else if (z == 1) { in = Wq;  out = WqT;  R = 768; C = 512;  }
    else             { in = Wo;  out = WoT;  R = 512; C = 768;  }
    int C0 = bx * 64, R0 = by * 64;
    if (C0 >= C || R0 >= R) return;      // uniform early-out (before any sync)
    int tc = threadIdx.x & 63, tr4 = threadIdx.x >> 6;
#pragma unroll
    for (int j = 0; j < 16; j++) {
        int r = tr4 + j * 4;
        tile[r][tc] = f2bf(in[(size_t)(R0 + r) * C + C0 + tc]);
    }
    __syncthreads();
#pragma unroll
    for (int j = 0; j < 16; j++) {
        int c = tr4 + j * 4;
        out[(size_t)(C0 + c) * R + R0 + tc] = tile[tc][c];
    }
}

// --------------- fused KV + Q projection GEMM (128^2, K=768) ---------------
// blocks [0, KV_BLOCKS)        : kvb[66048][1024] = ctx @ WkvT^T, T1 swizzle
// blocks [KV_BLOCKS, +Q_BLOCKS): qfb[512][512]   = qin @ WqT^T (tail round)
// SINGLE bf16 output path; all per-block selections are wave-uniform (SGPR).
__global__ __launch_bounds__(256) void gemm_kvq(
        const ushort* __restrict__ ctx, const ushort* __restrict__ WkvT,
        ushort* __restrict__ kvb, const ushort* __restrict__ qin,
        const ushort* __restrict__ WqT, ushort* __restrict__ qfb) {
    __shared__ ushort lA[128 * 64];
    __shared__ ushort lB[128 * 64];
    int tid = threadIdx.x;
    int lane = tid & 63, wave = tid >> 6;
    int wm = wave >> 1, wn = wave & 1;

    int lin = blockIdx.x;
    const ushort *A, *B;
    ushort* Cp;
    int bm, bn, N;
    if (lin < KV_BLOCKS) {
        int swz = (lin & 7) * (KV_BLOCKS >> 3) + (lin >> 3);   // T1, 4128%8==0
        bn = swz & 7; bm = swz >> 3;                           // 8 col-tiles
        A = ctx; B = WkvT; Cp = kvb; N = 1024;
    } else {
        int l2 = lin - KV_BLOCKS;
        bn = l2 & 3; bm = l2 >> 2;                             // 4 x 4
        A = qin; B = WqT; Cp = qfb; N = 512;
    }
    const int K = DIMK;                                        // 768 for both

    floatx4 acc[4][4];
#pragma unroll
    for (int mi = 0; mi < 4; mi++)
#pragma unroll
        for (int ni = 0; ni < 4; ni++) acc[mi][ni] = (floatx4){0.f, 0.f, 0.f, 0.f};

    int srow = lane >> 3;
    int schunk = (lane & 7) ^ srow;
    int quad = lane >> 4, lr = lane & 15;
    const int kiters = K >> 6;                                 // 12

    for (int kt = 0; kt < kiters; kt++) {
#pragma unroll
        for (int c2 = 0; c2 < 4; c2++) {
            int row = c2 * 32 + wave * 8 + srow;
            const ushort* gpA = A + ((size_t)(bm * 128 + row) * K + kt * 64 + schunk * 8);
            ushort* lpA = lA + (c2 * 32 + wave * 8) * 64 + lane * 8;
            __builtin_amdgcn_global_load_lds((gvoid*)gpA, (lvoid*)lpA, 16, 0, 0);
            const ushort* gpB = B + ((size_t)(bn * 128 + row) * K + kt * 64 + schunk * 8);
            ushort* lpB = lB + (c2 * 32 + wave * 8) * 64 + lane * 8;
            __builtin_amdgcn_global_load_lds((gvoid*)gpB, (lvoid*)lpB, 16, 0, 0);
        }
        __syncthreads();
#pragma unroll
        for (int ks = 0; ks < 2; ks++) {
            short8 av[4], bv[4];
            int slot = ((ks * 4 + quad) ^ (lane & 7)) * 8;
#pragma unroll
            for (int mi = 0; mi < 4; mi++)
                av[mi] = *(const short8*)(lA + (wm * 64 + mi * 16 + lr) * 64 + slot);
#pragma unroll
            for (int ni = 0; ni < 4; ni++)
                bv[ni] = *(const short8*)(lB + (wn * 64 + ni * 16 + lr) * 64 + slot);
#pragma unroll
            for (int mi = 0; mi < 4; mi++)
#pragma unroll
                for (int ni = 0; ni < 4; ni++)
                    acc[mi][ni] = __builtin_amdgcn_mfma_f32_16x16x32_bf16(
                        av[mi], bv[ni], acc[mi][ni], 0, 0, 0);
        }
        __syncthreads();
    }
#pragma unroll
    for (int mi = 0; mi < 4; mi++)
#pragma unroll
        for (int ni = 0; ni < 4; ni++)
#pragma unroll
            for (int r = 0; r < 4; r++) {
                int row = bm * 128 + wm * 64 + mi * 16 + quad * 4 + r;
                int col = bn * 128 + wn * 64 + ni * 16 + lr;
                Cp[(size_t)row * N + col] = f2bf(acc[mi][ni][r]);
            }
}

// ------------------------------- GEMM (128^2) ------------------------------
// C[M][N] = A[M][K] @ B[N][K]^T , A/B bf16, acc fp32. T1 XCD swizzle
// (nwg must be %8==0; final out-gemm grid is 24). Used for the Wo GEMM.
template <typename CT>
__global__ __launch_bounds__(256) void gemm_bt(
        const ushort* __restrict__ A, const ushort* __restrict__ B,
        CT* __restrict__ C, int M, int N, int K) {
    __shared__ ushort lA[128 * 64];
    __shared__ ushort lB[128 * 64];
    int tid = threadIdx.x;
    int lane = tid & 63, wave = tid >> 6;
    int wm = wave >> 1, wn = wave & 1;

    int nwg = gridDim.x * gridDim.y;
    int lin = blockIdx.y * gridDim.x + blockIdx.x;
    int swz = (lin & 7) * (nwg >> 3) + (lin >> 3);
    int bn = swz % gridDim.x, bm = swz / gridDim.x;

    floatx4 acc[4][4];
#pragma unroll
    for (int mi = 0; mi < 4; mi++)
#pragma unroll
        for (int ni = 0; ni < 4; ni++) acc[mi][ni] = (floatx4){0.f, 0.f, 0.f, 0.f};

    int srow = lane >> 3;
    int schunk = (lane & 7) ^ srow;
    int quad = lane >> 4, lr = lane & 15;
    const int kiters = K >> 6;

    for (int kt = 0; kt < kiters; kt++) {
#pragma unroll
        for (int c2 = 0; c2 < 4; c2++) {
            int row = c2 * 32 + wave * 8 + srow;
            const ushort* gpA = A + ((size_t)(bm * 128 + row) * K + kt * 64 + schunk * 8);
            ushort* lpA = lA + (c2 * 32 + wave * 8) * 64 + lane * 8;
            __builtin_amdgcn_global_load_lds((gvoid*)gpA, (lvoid*)lpA, 16, 0, 0);
            const ushort* gpB = B + ((size_t)(bn * 128 + row) * K + kt * 64 + schunk * 8);
            ushort* lpB = lB + (c2 * 32 + wave * 8) * 64 + lane * 8;
            __builtin_amdgcn_global_load_lds((gvoid*)gpB, (lvoid*)lpB, 16, 0, 0);
        }
        __syncthreads();
#pragma unroll
        for (int ks = 0; ks < 2; ks++) {
            short8 av[4], bv[4];
            int slot = ((ks * 4 + quad) ^ (lane & 7)) * 8;
#pragma unroll
            for (int mi = 0; mi < 4; mi++)
                av[mi] = *(const short8*)(lA + (wm * 64 + mi * 16 + lr) * 64 + slot);
#pragma unroll
            for (int ni = 0; ni < 4; ni++)
                bv[ni] = *(const short8*)(lB + (wn * 64 + ni * 16 + lr) * 64 + slot);
#pragma unroll
            for (int mi = 0; mi < 4; mi++)
#pragma unroll
                for (int ni = 0; ni < 4; ni++)
                    acc[mi][ni] = __builtin_amdgcn_mfma_f32_16x16x32_bf16(
                        av[mi], bv[ni], acc[mi][ni], 0, 0, 0);
        }
        __syncthreads();
    }
#pragma unroll
    for (int mi = 0; mi < 4; mi++)
#pragma unroll
        for (int ni = 0; ni < 4; ni++)
#pragma unroll
            for (int r = 0; r < 4; r++) {
                int row = bm * 128 + wm * 64 + mi * 16 + quad * 4 + r;
                int col = bn * 128 + wn * 64 + ni * 16 + lr;
                float vv = acc[mi][ni][r];
                if constexpr (std::is_same<CT, ushort>::value)
                    C[(size_t)row * N + col] = f2bf(vv);
                else
                    C[(size_t)row * N + col] = vv;
            }
}

// ------------------------- flash attention (split-K) -----------------------
// Wave-local softmax: wave w owns Q/O rows [w*16, w*16+16). Per 128-key tile:
// S rows for ALL 128 keys live in-wave (8 C-frags); online-softmax reductions
// are 16-lane shfl_xor. lP is wave-private. 2 __syncthreads per tile.
// PR = 136 keeps lP/lVT rows 16B-aligned with 2-way bank aliasing (free).
// Q input is bf16 (qfb) -- direct short8 A-frag loads.
#define PR 136

__global__ __launch_bounds__(256) void attn_flash(
        const ushort* __restrict__ qfb, const ushort* __restrict__ kvb,
        float* __restrict__ Op, float* __restrict__ ml) {
    __shared__ ushort lK[128 * 64];
    __shared__ ushort lVT[64 * PR];   // [d 0..63][key 0..127]
    __shared__ ushort lP[64 * PR];    // [qrow 0..63][key 0..127], wave-private rows

    int comb = blockIdx.x, split = blockIdx.y;
    int bt = comb >> 3, h = comb & 7;
    int tid = threadIdx.x;
    int w = tid >> 6, lane = tid & 63, quad = lane >> 4, lr = lane & 15;

    const ushort* kptr = kvb + (size_t)bt * N_CTX * 1024 + h * 64;
    const ushort* vptr = kptr + 512;

    short8 qa[2];
    {
        const ushort* p0 = qfb + (size_t)(bt * 64 + w * 16 + lr) * DEMB + h * 64;
        qa[0] = *(const short8*)(p0 + quad * 8);
        qa[1] = *(const short8*)(p0 + 32 + quad * 8);
    }

    floatx4 accO[4];
#pragma unroll
    for (int nt = 0; nt < 4; nt++) accO[nt] = (floatx4){0.f, 0.f, 0.f, 0.f};
    float m_run[4], l_run[4];
#pragma unroll
    for (int r = 0; r < 4; r++) { m_run[r] = -1e30f; l_run[r] = 0.f; }

    for (int t = split; t < NTILES; t += NSPLIT) {
        int kbase = t * 128;
        __syncthreads();   // prev-iter lK/lVT readers done before restaging

#pragma unroll
        for (int c2 = 0; c2 < 4; c2++) {
            int jloc = w * 32 + c2 * 8 + (lane >> 3);
            int chunk = (lane & 7) ^ ((lane >> 3) & 7);
            int jg = kbase + jloc; if (jg > N_CTX - 1) jg = N_CTX - 1;  // clamp tail
            const ushort* gp = kptr + (size_t)jg * 1024 + chunk * 8;
            ushort* lp = lK + (w * 32 + c2 * 8) * 64 + lane * 8;
            __builtin_amdgcn_global_load_lds((gvoid*)gp, (lvoid*)lp, 16, 0, 0);
        }

        {
            int k0 = kbase + lane * 2;
            bool valid = (k0 + 1) < N_CTX;
            int k0c = valid ? k0 : (N_CTX - 2);
            const ushort* r0 = vptr + (size_t)k0c * 1024 + w * 16;
            const ushort* r1 = r0 + 1024;
            uint4 a0 = *(const uint4*)r0;
            uint4 a1 = *(const uint4*)(r0 + 8);
            uint4 b0 = *(const uint4*)r1;
            uint4 b1 = *(const uint4*)(r1 + 8);
            if (!valid) {
                a0 = make_uint4(0, 0, 0, 0); a1 = a0; b0 = a0; b1 = a0;
            }
            unsigned av8[8] = {a0.x, a0.y, a0.z, a0.w, a1.x, a1.y, a1.z, a1.w};
            unsigned bv8[8] = {b0.x, b0.y, b0.z, b0.w, b1.x, b1.y, b1.z, b1.w};
#pragma unroll
            for (int i = 0; i < 8; i++) {
                unsigned la = av8[i] & 0xffffu, ha = av8[i] >> 16;
                unsigned lb = bv8[i] & 0xffffu, hb = bv8[i] >> 16;
                *(unsigned*)(lVT + (w * 16 + 2 * i) * PR + lane * 2)     = la | (lb << 16);
                *(unsigned*)(lVT + (w * 16 + 2 * i + 1) * PR + lane * 2) = ha | (hb << 16);
            }
        }
        __syncthreads();   // staging complete

        floatx4 accS[8];
#pragma unroll
        for (int nt = 0; nt < 8; nt++) accS[nt] = (floatx4){0.f, 0.f, 0.f, 0.f};
#pragma unroll
        for (int kc = 0; kc < 2; kc++) {
#pragma unroll
            for (int nt = 0; nt < 8; nt++) {
                int kr = nt * 16 + lr;
                int slot = (kc * 4 + quad) ^ (kr & 7);
                short8 bv = *(const short8*)(lK + kr * 64 + slot * 8);
                accS[nt] = __builtin_amdgcn_mfma_f32_16x16x32_bf16(
                    qa[kc], bv, accS[nt], 0, 0, 0);
            }
        }

        float sc[8][4];
        float tmax[4] = {-1e30f, -1e30f, -1e30f, -1e30f};
#pragma unroll
        for (int nt = 0; nt < 8; nt++) {
            bool vk = (kbase + nt * 16 + lr) < N_CTX;
#pragma unroll
            for (int r = 0; r < 4; r++) {
                float s = vk ? accS[nt][r] * 0.125f : -1e30f;
                sc[nt][r] = s;
                tmax[r] = fmaxf(tmax[r], s);
            }
        }
#pragma unroll
        for (int r = 0; r < 4; r++) {
#pragma unroll
            for (int d = 1; d < 16; d <<= 1) tmax[r] = fmaxf(tmax[r], __shfl_xor(tmax[r], d, 64));
        }
        float alpha[4], lsum[4];
#pragma unroll
        for (int r = 0; r < 4; r++) {
            float mn = fmaxf(m_run[r], tmax[r]);
            alpha[r] = __expf(m_run[r] - mn);
            m_run[r] = mn;
            lsum[r] = 0.f;
        }

#pragma unroll
        for (int nt = 0; nt < 8; nt++) {
#pragma unroll
            for (int r = 0; r < 4; r++) {
                float p = __expf(sc[nt][r] - m_run[r]);
                lsum[r] += p;
                lP[(w * 16 + quad * 4 + r) * PR + nt * 16 + lr] = f2bf(p);
            }
        }
#pragma unroll
        for (int r = 0; r < 4; r++) {
#pragma unroll
            for (int d = 1; d < 16; d <<= 1) lsum[r] += __shfl_xor(lsum[r], d, 64);
            l_run[r] = l_run[r] * alpha[r] + lsum[r];
        }
#pragma unroll
        for (int nt = 0; nt < 4; nt++) {
            accO[nt][0] *= alpha[0]; accO[nt][1] *= alpha[1];
            accO[nt][2] *= alpha[2]; accO[nt][3] *= alpha[3];
        }

        short8 av[4];
#pragma unroll
        for (int kc = 0; kc < 4; kc++)
            av[kc] = *(const short8*)(lP + (w * 16 + lr) * PR + kc * 32 + quad * 8);
#pragma unroll
        for (int nt = 0; nt < 4; nt++)
#pragma unroll
            for (int kc = 0; kc < 4; kc++) {
                short8 bv = *(const short8*)(lVT + (nt * 16 + lr) * PR + kc * 32 + quad * 8);
                accO[nt] = __builtin_amdgcn_mfma_f32_16x16x32_bf16(av[kc], bv, accO[nt], 0, 0, 0);
            }
    }

    float* opb = Op + (size_t)(comb * NSPLIT + split) * 64 * 64;
#pragma unroll
    for (int nt = 0; nt < 4; nt++)
#pragma unroll
        for (int r = 0; r < 4; r++)
            opb[(w * 16 + quad * 4 + r) * 64 + nt * 16 + lr] = accO[nt][r];
    if (lr == 0) {
#pragma unroll
        for (int r = 0; r < 4; r++) {
            int row = w * 16 + quad * 4 + r;
            float* mlp = ml + ((size_t)(comb * NSPLIT + split) * 64 + row) * 2;
            mlp[0] = m_run[r]; mlp[1] = l_run[r];
        }
    }
}

__global__ __launch_bounds__(64) void attn_combine(
        const float* __restrict__ Op, const float* __restrict__ ml,
        ushort* __restrict__ outp) {
    int bx = blockIdx.x;
    int comb = bx >> 6, q = bx & 63;
    int bt = comb >> 3, h = comb & 7;
    int d = threadIdx.x;
    float M = -1e30f;
    for (int s = 0; s < NSPLIT; s++)
        M = fmaxf(M, ml[((size_t)(comb * NSPLIT + s) * 64 + q) * 2]);
    float L = 0.f, O = 0.f;
    for (int s = 0; s < NSPLIT; s++) {
        const float* p = ml + ((size_t)(comb * NSPLIT + s) * 64 + q) * 2;
        float wgt = __expf(p[0] - M);
        L = fmaf(wgt, p[1], L);
        O = fmaf(wgt, Op[((size_t)(comb * NSPLIT + s) * 64 + q) * 64 + d], O);
    }
    outp[(size_t)(bt * 64 + q) * DEMB + h * 64 + d] = f2bf(O / L);
}

// ------------------------------ launcher -----------------------------------
extern "C" void kernel_launch(void* const* d_in, const int* in_sizes, int n_in,
                              void* d_out, int out_size, void* d_ws, size_t ws_size,
                              hipStream_t stream) {
    const float* src   = (const float*)d_in[0];
    const float* ltn   = (const float*)d_in[1];
    const float* g_src = (const float*)d_in[2];
    const float* b_src = (const float*)d_in[3];
    const float* g_ltn = (const float*)d_in[4];
    const float* b_ltn = (const float*)d_in[5];
    const float* Wq    = (const float*)d_in[6];
    const float* Wkv   = (const float*)d_in[7];
    const float* Wo    = (const float*)d_in[8];
    float* out = (float*)d_out;

    char* ws = (char*)d_ws;
    size_t off = 0;
    auto alloc = [&](size_t bytes) -> void* {
        void* p = ws + off;
        off += (bytes + 255) & ~(size_t)255;
        return p;
    };
    ushort* ctx  = (ushort*)alloc((size_t)MROWS * DIMK * 2);   // 101.4 MB
    ushort* qin  = (ushort*)alloc((size_t)512 * DIMK * 2);
    ushort* WkvT = (ushort*)alloc((size_t)1024 * DIMK * 2);
    ushort* WqT  = (ushort*)alloc((size_t)512 * DIMK * 2);
    ushort* WoT  = (ushort*)alloc((size_t)768 * DEMB * 2);
    ushort* kvb  = (ushort*)alloc((size_t)MROWS * 1024 * 2);   // 135.3 MB
    ushort* qfb  = (ushort*)alloc((size_t)512 * DEMB * 2);
    ushort* outp = (ushort*)alloc((size_t)512 * DEMB * 2);

    // attention partials alias the ctx buffer (dead after the fused GEMM)
    float* Op  = (float*)(void*)ctx;                       // 16.8 MB
    float* mlb = Op + (size_t)64 * NSPLIT * 64 * 64;

    // 1) transposes + layernorm (independent halves, one launch)
    prep_kernel<<<LN_BLOCKS + TR_BLOCKS, 256, 0, stream>>>(
        src, ltn, g_src, b_src, g_ltn, b_ltn, ctx, qin,
        Wkv, Wq, Wo, WkvT, WqT, WoT);

    // 2) KV projection (4128 blk, T1 swizzle) + Q projection (16 blk in tail)
    gemm_kvq<<<KV_BLOCKS + Q_BLOCKS, 256, 0, stream>>>(
        ctx, WkvT, kvb, qin, WqT, qfb);

    // 3-4) attention
    attn_flash<<<dim3(64, NSPLIT), 256, 0, stream>>>(qfb, kvb, Op, mlb);
    attn_combine<<<4096, 64, 0, stream>>>(Op, mlb, outp);

    // 5) output projection (grid 24, 24%8==0 for T1)
    gemm_bt<float><<<dim3(768 / 128, 512 / 128), 256, 0, stream>>>(
        outp, WoT, out, 512, 768, DEMB);
}